// Round 1
// baseline (385.618 us; speedup 1.0000x reference)
//
#include <hip/hip_runtime.h>
#include <hip/hip_bf16.h>

#define D  128
#define KN 32

typedef __attribute__((ext_vector_type(8))) short bf16x8;
typedef __attribute__((ext_vector_type(4))) float f32x4;

static __device__ __forceinline__ unsigned short f2bf(float f) {
    union { float f; unsigned int u; } v; v.f = f;
    unsigned int u = v.u;
    u += 0x7fff + ((u >> 16) & 1);   // round-to-nearest-even
    return (unsigned short)(u >> 16);
}
static __device__ __forceinline__ float bf2f(unsigned short h) {
    union { float f; unsigned int u; } v; v.u = ((unsigned int)h) << 16;
    return v.f;
}

// Stage a 128x128 fp32 weight matrix (row-major [e][d]) transposed into LDS
// as bf16 sW[d][e], padded row stride 136 (272B = 17*16B: keeps 16B alignment,
// bank shift 4 words/row).
__device__ __forceinline__ void stage_wt(const float* __restrict__ W,
                                         unsigned short sW[D][136], int tid) {
#pragma unroll
    for (int i = 0; i < 16; ++i) {
        int base = (tid + 256 * i) * 4;          // 16384 elements total
        int e = base >> 7, d0 = base & 127;
        const float4 rd = *(const float4*)(W + base);
        sW[d0 + 0][e] = f2bf(rd.x);
        sW[d0 + 1][e] = f2bf(rd.y);
        sW[d0 + 2][e] = f2bf(rd.z);
        sW[d0 + 3][e] = f2bf(rd.w);
    }
}

// dst[r][:] = (emb[gidx? gidx[r] : r] @ W[0:128][:]) + bias   (bf16 out)
// One block = 64 rows, 4 waves, each wave one 16-row M-tile x all 8 N-tiles.
__global__ __launch_bounds__(256) void p1q_kernel(
    const float* __restrict__ emb, const int* __restrict__ gidx, int M,
    const float* __restrict__ W, const float* __restrict__ bias,
    unsigned short* __restrict__ dst)
{
    __shared__ unsigned short sW[D][136];     // W^T : sW[n][k]
    __shared__ unsigned short sA[64][136];

    const int tid  = threadIdx.x;
    const int lane = tid & 63;
    const int w    = tid >> 6;
    const int r0   = blockIdx.x * 64;

    stage_wt(W, sW, tid);

    // stage 64 A rows (gather + fp32->bf16), float4-vectorized
#pragma unroll
    for (int i = 0; i < 8; ++i) {
        int idx = tid + 256 * i;                 // 2048 float4 loads
        int row = idx >> 5, c4 = (idx & 31) << 2;
        int r = r0 + row; if (r > M - 1) r = M - 1;
        int vr = gidx ? gidx[r] : r;
        const float4 f = *(const float4*)(emb + (long)vr * D + c4);
        ushort4 h;
        h.x = f2bf(f.x); h.y = f2bf(f.y); h.z = f2bf(f.z); h.w = f2bf(f.w);
        *(ushort4*)(&sA[row][c4]) = h;
    }
    __syncthreads();

    const int m = lane & 15, q = lane >> 4;
    f32x4 acc[8];
#pragma unroll
    for (int t = 0; t < 8; ++t) acc[t] = (f32x4){0.f, 0.f, 0.f, 0.f};

#pragma unroll
    for (int kk = 0; kk < 4; ++kk) {
        bf16x8 a = *(const bf16x8*)(&sA[16 * w + m][kk * 32 + q * 8]);
#pragma unroll
        for (int t = 0; t < 8; ++t) {
            bf16x8 b = *(const bf16x8*)(&sW[16 * t + m][kk * 32 + q * 8]);
            acc[t] = __builtin_amdgcn_mfma_f32_16x16x32_bf16(a, b, acc[t], 0, 0, 0);
        }
    }

    // epilogue: C/D layout col=lane&15, row=(lane>>4)*4+reg
#pragma unroll
    for (int t = 0; t < 8; ++t) {
        int col = 16 * t + m;
        float bv = bias ? bias[col] : 0.f;
#pragma unroll
        for (int r = 0; r < 4; ++r) {
            int row = r0 + 16 * w + 4 * q + r;
            if (row < M) dst[(long)row * D + col] = f2bf(acc[t][r] + bv);
        }
    }
}

// Fused per-node: X = relu(P1[nidx[k]] + Q[node]); h2 = relu(X@W2+b2);
// score = h2@W3+b3; softmax; out = sum_k att_k * emb[nidx[k]] (fp32).
__global__ __launch_bounds__(256) void agg_kernel(
    const float* __restrict__ emb,
    const int* __restrict__ nidx,
    const float* __restrict__ W2, const float* __restrict__ b2,
    const float* __restrict__ W3, const float* __restrict__ b3,
    const unsigned short* __restrict__ P1, const unsigned short* __restrict__ Q,
    float* __restrict__ out, int NN)
{
    __shared__ unsigned short sW[D][136];
    __shared__ unsigned short sX[KN][136];
    __shared__ int   sIdx[KN];
    __shared__ float sSp[4][KN];
    __shared__ float sAtt[KN];

    const int tid  = threadIdx.x;
    const int lane = tid & 63;
    const int w    = tid >> 6;
    const int m    = lane & 15, q = lane >> 4;

    stage_wt(W2, sW, tid);

    // per-lane constants for this wave's 32-col slice
    float b2v[2], w3v[2];
#pragma unroll
    for (int nt = 0; nt < 2; ++nt) {
        int col = 32 * w + 16 * nt + m;
        b2v[nt] = b2[col];
        w3v[nt] = W3[col];
    }
    const float b3s = b3[0];

    for (int node = blockIdx.x; node < NN; node += gridDim.x) {
        // ---- stage X (32 rows x 128, bf16), 8 threads per row ----
        {
            int k = tid >> 3, t8 = tid & 7;
            int ni = nidx[node * KN + k];
            if (t8 == 0) sIdx[k] = ni;
            const bf16x8* pr = (const bf16x8*)(P1 + (long)ni * D + t8 * 16);
            const bf16x8* qr = (const bf16x8*)(Q + (long)node * D + t8 * 16);
            bf16x8 p0 = pr[0], p1v = pr[1];
            bf16x8 q0 = qr[0], q1v = qr[1];
            bf16x8 r0v, r1v;
#pragma unroll
            for (int h = 0; h < 8; ++h) {
                float v0 = bf2f((unsigned short)p0[h]) + bf2f((unsigned short)q0[h]);
                float v1 = bf2f((unsigned short)p1v[h]) + bf2f((unsigned short)q1v[h]);
                r0v[h] = (short)f2bf(v0 > 0.f ? v0 : 0.f);
                r1v[h] = (short)f2bf(v1 > 0.f ? v1 : 0.f);
            }
            *(bf16x8*)(&sX[k][t8 * 16 + 0]) = r0v;
            *(bf16x8*)(&sX[k][t8 * 16 + 8]) = r1v;
        }
        __syncthreads();

        // ---- layer-2 GEMM: wave w owns cols [32w, 32w+32) ----
        f32x4 acc[2][2];
#pragma unroll
        for (int mt = 0; mt < 2; ++mt)
#pragma unroll
            for (int nt = 0; nt < 2; ++nt) acc[mt][nt] = (f32x4){0.f, 0.f, 0.f, 0.f};

#pragma unroll
        for (int kk = 0; kk < 4; ++kk) {
            bf16x8 a0 = *(const bf16x8*)(&sX[m][kk * 32 + q * 8]);
            bf16x8 a1 = *(const bf16x8*)(&sX[16 + m][kk * 32 + q * 8]);
            bf16x8 b0 = *(const bf16x8*)(&sW[32 * w + m][kk * 32 + q * 8]);
            bf16x8 b1 = *(const bf16x8*)(&sW[32 * w + 16 + m][kk * 32 + q * 8]);
            acc[0][0] = __builtin_amdgcn_mfma_f32_16x16x32_bf16(a0, b0, acc[0][0], 0, 0, 0);
            acc[0][1] = __builtin_amdgcn_mfma_f32_16x16x32_bf16(a0, b1, acc[0][1], 0, 0, 0);
            acc[1][0] = __builtin_amdgcn_mfma_f32_16x16x32_bf16(a1, b0, acc[1][0], 0, 0, 0);
            acc[1][1] = __builtin_amdgcn_mfma_f32_16x16x32_bf16(a1, b1, acc[1][1], 0, 0, 0);
        }

        // ---- relu+bias, dot with W3, reduce over this wave's 16 col-lanes ----
#pragma unroll
        for (int mt = 0; mt < 2; ++mt) {
            float p[4];
#pragma unroll
            for (int r = 0; r < 4; ++r) {
                float h0 = acc[mt][0][r] + b2v[0]; h0 = h0 > 0.f ? h0 : 0.f;
                float h1 = acc[mt][1][r] + b2v[1]; h1 = h1 > 0.f ? h1 : 0.f;
                p[r] = h0 * w3v[0] + h1 * w3v[1];
            }
#pragma unroll
            for (int off = 8; off >= 1; off >>= 1)
#pragma unroll
                for (int r = 0; r < 4; ++r) p[r] += __shfl_xor(p[r], off, 16);
            if (m == 0) {
#pragma unroll
                for (int r = 0; r < 4; ++r) sSp[w][16 * mt + 4 * q + r] = p[r];
            }
        }
        __syncthreads();

        // ---- softmax over 32 scores (wave 0, lanes 0..31) ----
        if (tid < KN) {
            float s = sSp[0][tid] + sSp[1][tid] + sSp[2][tid] + sSp[3][tid] + b3s;
            float mx = s;
#pragma unroll
            for (int off = 16; off >= 1; off >>= 1) mx = fmaxf(mx, __shfl_xor(mx, off, 32));
            float e = __expf(s - mx);
            float sum = e;
#pragma unroll
            for (int off = 16; off >= 1; off >>= 1) sum += __shfl_xor(sum, off, 32);
            sAtt[tid] = e / sum;
        }
        __syncthreads();

        // ---- fp32 aggregation: out[node][d] = sum_k att[k]*emb[idx[k]][d] ----
        if (tid < D) {
            float a = 0.f;
#pragma unroll
            for (int k = 0; k < KN; ++k)
                a += sAtt[k] * emb[(long)sIdx[k] * D + tid];
            out[(long)node * D + tid] = a;
        }
        __syncthreads();   // protect sX/sIdx/sSp before next iteration
    }
}

// Correct-but-slow fp32 VALU fallback (only if ws is too small for P1/Q).
__global__ __launch_bounds__(128) void naive_kernel(
    const float* __restrict__ emb, const int* __restrict__ vnodes,
    const int* __restrict__ nidx,
    const float* __restrict__ W1, const float* __restrict__ b1,
    const float* __restrict__ W2, const float* __restrict__ b2,
    const float* __restrict__ W3, const float* __restrict__ b3,
    float* __restrict__ out)
{
    __shared__ float sE[KN + 1][D];
    __shared__ float sH[KN][D];
    __shared__ float sH2[KN][D];
    __shared__ float sS[KN];
    __shared__ float sA2[KN];
    const int node = blockIdx.x, tid = threadIdx.x;

    for (int r = 0; r < KN + 1; ++r) {
        int vr = (r < KN) ? nidx[node * KN + r] : vnodes[node];
        sE[r][tid] = emb[(long)vr * D + tid];
    }
    __syncthreads();
    for (int k = 0; k < KN; ++k) {
        float s = b1[tid];
        for (int e = 0; e < D; ++e) s += sE[k][e]  * W1[e * D + tid];
        for (int e = 0; e < D; ++e) s += sE[KN][e] * W1[(D + e) * D + tid];
        sH[k][tid] = s > 0.f ? s : 0.f;
    }
    __syncthreads();
    for (int k = 0; k < KN; ++k) {
        float s = b2[tid];
        for (int e = 0; e < D; ++e) s += sH[k][e] * W2[e * D + tid];
        sH2[k][tid] = s > 0.f ? s : 0.f;
    }
    __syncthreads();
    if (tid < KN) {
        float s = b3[0];
        for (int e = 0; e < D; ++e) s += sH2[tid][e] * W3[e];
        sS[tid] = s;
    }
    __syncthreads();
    if (tid == 0) {
        float mx = sS[0];
        for (int k = 1; k < KN; ++k) mx = fmaxf(mx, sS[k]);
        float sum = 0.f;
        for (int k = 0; k < KN; ++k) { sA2[k] = __expf(sS[k] - mx); sum += sA2[k]; }
        for (int k = 0; k < KN; ++k) sA2[k] /= sum;
    }
    __syncthreads();
    float a = 0.f;
    for (int k = 0; k < KN; ++k) a += sA2[k] * sE[k][tid];
    out[(long)node * D + tid] = a;
}

extern "C" void kernel_launch(void* const* d_in, const int* in_sizes, int n_in,
                              void* d_out, int out_size, void* d_ws, size_t ws_size,
                              hipStream_t stream) {
    const float* emb    = (const float*)d_in[0];
    const int*   vnodes = (const int*)d_in[1];
    const int*   nidx   = (const int*)d_in[2];
    const float* W1     = (const float*)d_in[3];
    const float* b1     = (const float*)d_in[4];
    const float* W2     = (const float*)d_in[5];
    const float* b2     = (const float*)d_in[6];
    const float* W3     = (const float*)d_in[7];
    const float* b3     = (const float*)d_in[8];
    float* out = (float*)d_out;

    const int NV = in_sizes[0] / D;   // 200000
    const int NN = in_sizes[1];       // 20000

    const size_t p1_elems = (size_t)NV * D;
    const size_t q_elems  = (size_t)NN * D;
    const size_t need = (p1_elems + q_elems) * sizeof(unsigned short);

    if (ws_size >= need) {
        unsigned short* P1 = (unsigned short*)d_ws;
        unsigned short* Q  = (unsigned short*)d_ws + p1_elems;
        p1q_kernel<<<(NV + 63) / 64, 256, 0, stream>>>(emb, nullptr, NV, W1, nullptr, P1);
        p1q_kernel<<<(NN + 63) / 64, 256, 0, stream>>>(emb, vnodes, NN, W1 + D * D, b1, Q);
        agg_kernel<<<1024, 256, 0, stream>>>(emb, nidx, W2, b2, W3, b3, P1, Q, out, NN);
    } else {
        naive_kernel<<<NN, D, 0, stream>>>(emb, vnodes, nidx, W1, b1, W2, b2, W3, b3, out);
    }
}

// Round 2
// 325.879 us; speedup vs baseline: 1.1833x; 1.1833x over previous
//
#include <hip/hip_runtime.h>
#include <hip/hip_bf16.h>

#define D  128
#define KN 32

typedef __attribute__((ext_vector_type(8))) short bf16x8;
typedef __attribute__((ext_vector_type(4))) float f32x4;

static __device__ __forceinline__ unsigned short f2bf(float f) {
    union { float f; unsigned int u; } v; v.f = f;
    unsigned int u = v.u;
    u += 0x7fff + ((u >> 16) & 1);   // round-to-nearest-even
    return (unsigned short)(u >> 16);
}
static __device__ __forceinline__ float bf2f(unsigned short h) {
    union { float f; unsigned int u; } v; v.u = ((unsigned int)h) << 16;
    return v.f;
}

// One-shot: transpose+convert W1 top half, W1 bottom half, W2 into bf16
// [col][k] layouts so every GEMM block can load B-fragments directly from
// global (L2-resident, no per-block LDS staging/conversion).
__global__ __launch_bounds__(256) void wt_kernel(
    const float* __restrict__ W1, const float* __restrict__ W2,
    unsigned short* __restrict__ W1Tt, unsigned short* __restrict__ W1Tb,
    unsigned short* __restrict__ W2T)
{
    int idx = blockIdx.x * 256 + threadIdx.x;
    if (idx < D * D) {
        int col = idx >> 7, e = idx & 127;
        W1Tt[col * D + e] = f2bf(W1[e * D + col]);
        W1Tb[col * D + e] = f2bf(W1[(D + e) * D + col]);
        W2T [col * D + e] = f2bf(W2[e * D + col]);
    }
}

// dst[r][:] = (emb[gidx? gidx[r] : r] @ W) + bias   (bf16 out)
// 128 rows/block. Waves split N (2 N-tiles each, B-frags in registers);
// each wave covers all 8 M-tiles. 64 MFMA / wave / block.
__global__ __launch_bounds__(256) void p1q_kernel(
    const float* __restrict__ emb, const int* __restrict__ gidx, int M,
    const unsigned short* __restrict__ WT, const float* __restrict__ bias,
    unsigned short* __restrict__ dst)
{
    __shared__ unsigned short sA[128][136];   // +8 pad keeps 16B align, shifts banks

    const int tid  = threadIdx.x;
    const int lane = tid & 63;
    const int w    = tid >> 6;
    const int m    = lane & 15, q = lane >> 4;
    const int r0   = blockIdx.x * 128;

    // stage 128 gathered rows fp32->bf16 (4096 float4 loads)
#pragma unroll
    for (int i = 0; i < 16; ++i) {
        int e = tid + 256 * i;
        int row = e >> 5, c4 = (e & 31) << 2;
        int r = r0 + row; if (r > M - 1) r = M - 1;
        int vr = gidx ? gidx[r] : r;
        const float4 f = *(const float4*)(emb + (long)vr * D + c4);
        ushort4 h;
        h.x = f2bf(f.x); h.y = f2bf(f.y); h.z = f2bf(f.z); h.w = f2bf(f.w);
        *(ushort4*)(&sA[row][c4]) = h;
    }
    __syncthreads();

    // B fragments for this wave's 32-col slice (loaded after barrier to keep
    // staging-phase VGPR pressure low). col = 32w+16nt+m, k = kk*32+q*8.
    bf16x8 Bf[2][4];
#pragma unroll
    for (int nt = 0; nt < 2; ++nt)
#pragma unroll
        for (int kk = 0; kk < 4; ++kk)
            Bf[nt][kk] = *(const bf16x8*)(WT + (32 * w + 16 * nt + m) * D + kk * 32 + q * 8);
    float bv[2];
#pragma unroll
    for (int nt = 0; nt < 2; ++nt) bv[nt] = bias ? bias[32 * w + 16 * nt + m] : 0.f;

    f32x4 acc[8][2];
#pragma unroll
    for (int mt = 0; mt < 8; ++mt)
#pragma unroll
        for (int nt = 0; nt < 2; ++nt) acc[mt][nt] = (f32x4){0.f, 0.f, 0.f, 0.f};

#pragma unroll
    for (int kk = 0; kk < 4; ++kk) {
        bf16x8 a[8];
#pragma unroll
        for (int mt = 0; mt < 8; ++mt)
            a[mt] = *(const bf16x8*)(&sA[16 * mt + m][kk * 32 + q * 8]);
#pragma unroll
        for (int mt = 0; mt < 8; ++mt) {
            acc[mt][0] = __builtin_amdgcn_mfma_f32_16x16x32_bf16(a[mt], Bf[0][kk], acc[mt][0], 0, 0, 0);
            acc[mt][1] = __builtin_amdgcn_mfma_f32_16x16x32_bf16(a[mt], Bf[1][kk], acc[mt][1], 0, 0, 0);
        }
    }

    // C/D layout: col=lane&15, row=(lane>>4)*4+reg
#pragma unroll
    for (int mt = 0; mt < 8; ++mt)
#pragma unroll
        for (int nt = 0; nt < 2; ++nt) {
            int col = 32 * w + 16 * nt + m;
#pragma unroll
            for (int r = 0; r < 4; ++r) {
                int row = r0 + 16 * mt + 4 * q + r;
                if (row < M) dst[(long)row * D + col] = f2bf(acc[mt][nt][r] + bv[nt]);
            }
        }
}

// Fused per-node: X = relu(P1[nidx]+Q[node]); h2 = relu(X@W2+b2);
// score = h2@W3+b3; softmax over K; out = sum_k att_k * emb[nidx[k]].
// 2 nodes per iteration (64-row GEMM), W2 fragments register-resident.
__global__ __launch_bounds__(256) void agg_kernel(
    const float* __restrict__ emb,
    const int* __restrict__ nidx,
    const unsigned short* __restrict__ W2T,
    const float* __restrict__ b2, const float* __restrict__ W3,
    const float* __restrict__ b3,
    const unsigned short* __restrict__ P1, const unsigned short* __restrict__ Q,
    float* __restrict__ out, int NN)
{
    __shared__ unsigned short sX[64][136];
    __shared__ int   sIdx[64];
    __shared__ float sSp[4][64];
    __shared__ float sAtt[64];

    const int tid  = threadIdx.x;
    const int lane = tid & 63;
    const int w    = tid >> 6;
    const int m    = lane & 15, q = lane >> 4;

    // register-resident B fragments (W2T), per-wave 32-col slice
    bf16x8 Bf[2][4];
#pragma unroll
    for (int nt = 0; nt < 2; ++nt)
#pragma unroll
        for (int kk = 0; kk < 4; ++kk)
            Bf[nt][kk] = *(const bf16x8*)(W2T + (32 * w + 16 * nt + m) * D + kk * 32 + q * 8);
    float b2v[2], w3v[2];
#pragma unroll
    for (int nt = 0; nt < 2; ++nt) {
        int col = 32 * w + 16 * nt + m;
        b2v[nt] = b2[col];
        w3v[nt] = W3[col];
    }
    const float b3s = b3[0];

    const int pairs = (NN + 1) >> 1;
    for (int pr = blockIdx.x; pr < pairs; pr += gridDim.x) {
        const int node0 = pr * 2;

        // ---- stage 64 rows (2 nodes x 32 neighbors), 4 threads/row ----
        {
            int row = tid >> 2, t4 = tid & 3;
            int nd = node0 + (row >> 5); if (nd > NN - 1) nd = NN - 1;
            int k = row & 31;
            int ni = nidx[nd * KN + k];
            if (t4 == 0) sIdx[row] = ni;
            const bf16x8* pp = (const bf16x8*)(P1 + (long)ni * D);
            const bf16x8* qq = (const bf16x8*)(Q + (long)nd * D);
#pragma unroll
            for (int j = 0; j < 4; ++j) {
                int c = t4 * 4 + j;
                bf16x8 p = pp[c], qv = qq[c], r;
#pragma unroll
                for (int h = 0; h < 8; ++h) {
                    float v = bf2f((unsigned short)p[h]) + bf2f((unsigned short)qv[h]);
                    r[h] = (short)f2bf(v > 0.f ? v : 0.f);
                }
                *(bf16x8*)(&sX[row][c * 8]) = r;
            }
        }
        __syncthreads();

        // ---- layer-2 GEMM: 4 M-tiles x this wave's 2 N-tiles ----
        f32x4 acc[4][2];
#pragma unroll
        for (int mt = 0; mt < 4; ++mt)
#pragma unroll
            for (int nt = 0; nt < 2; ++nt) acc[mt][nt] = (f32x4){0.f, 0.f, 0.f, 0.f};

#pragma unroll
        for (int kk = 0; kk < 4; ++kk) {
            bf16x8 a[4];
#pragma unroll
            for (int mt = 0; mt < 4; ++mt)
                a[mt] = *(const bf16x8*)(&sX[16 * mt + m][kk * 32 + q * 8]);
#pragma unroll
            for (int mt = 0; mt < 4; ++mt) {
                acc[mt][0] = __builtin_amdgcn_mfma_f32_16x16x32_bf16(a[mt], Bf[0][kk], acc[mt][0], 0, 0, 0);
                acc[mt][1] = __builtin_amdgcn_mfma_f32_16x16x32_bf16(a[mt], Bf[1][kk], acc[mt][1], 0, 0, 0);
            }
        }

        // ---- relu+bias, dot W3, reduce across 16 col-lanes ----
#pragma unroll
        for (int mt = 0; mt < 4; ++mt) {
            float p[4];
#pragma unroll
            for (int r = 0; r < 4; ++r) {
                float h0 = acc[mt][0][r] + b2v[0]; h0 = h0 > 0.f ? h0 : 0.f;
                float h1 = acc[mt][1][r] + b2v[1]; h1 = h1 > 0.f ? h1 : 0.f;
                p[r] = h0 * w3v[0] + h1 * w3v[1];
            }
#pragma unroll
            for (int off = 8; off >= 1; off >>= 1)
#pragma unroll
                for (int r = 0; r < 4; ++r) p[r] += __shfl_xor(p[r], off, 16);
            if (m == 0) {
#pragma unroll
                for (int r = 0; r < 4; ++r) sSp[w][16 * mt + 4 * q + r] = p[r];
            }
        }
        __syncthreads();

        // ---- softmax: wave 0, lanes 0..63 = 2 nodes x 32 scores ----
        if (tid < 64) {
            float s = sSp[0][tid] + sSp[1][tid] + sSp[2][tid] + sSp[3][tid] + b3s;
            float mx = s;
#pragma unroll
            for (int off = 16; off >= 1; off >>= 1) mx = fmaxf(mx, __shfl_xor(mx, off, 32));
            float e = __expf(s - mx);
            float sum = e;
#pragma unroll
            for (int off = 16; off >= 1; off >>= 1) sum += __shfl_xor(sum, off, 32);
            sAtt[tid] = e / sum;
        }
        __syncthreads();

        // ---- fp32 aggregation: 2 nodes x 128 cols = all 256 threads ----
        {
            int ln = tid >> 7, dcol = tid & 127;
            float a = 0.f;
#pragma unroll
            for (int k = 0; k < KN; ++k)
                a += sAtt[ln * KN + k] * emb[(long)sIdx[ln * KN + k] * D + dcol];
            int nd = node0 + ln;
            if (nd < NN) out[(long)nd * D + dcol] = a;
        }
        __syncthreads();   // protect shared buffers before next iteration
    }
}

// Correct-but-slow fp32 VALU fallback (only if ws is too small).
__global__ __launch_bounds__(128) void naive_kernel(
    const float* __restrict__ emb, const int* __restrict__ vnodes,
    const int* __restrict__ nidx,
    const float* __restrict__ W1, const float* __restrict__ b1,
    const float* __restrict__ W2, const float* __restrict__ b2,
    const float* __restrict__ W3, const float* __restrict__ b3,
    float* __restrict__ out)
{
    __shared__ float sE[KN + 1][D];
    __shared__ float sH[KN][D];
    __shared__ float sH2[KN][D];
    __shared__ float sS[KN];
    __shared__ float sA2[KN];
    const int node = blockIdx.x, tid = threadIdx.x;

    for (int r = 0; r < KN + 1; ++r) {
        int vr = (r < KN) ? nidx[node * KN + r] : vnodes[node];
        sE[r][tid] = emb[(long)vr * D + tid];
    }
    __syncthreads();
    for (int k = 0; k < KN; ++k) {
        float s = b1[tid];
        for (int e = 0; e < D; ++e) s += sE[k][e]  * W1[e * D + tid];
        for (int e = 0; e < D; ++e) s += sE[KN][e] * W1[(D + e) * D + tid];
        sH[k][tid] = s > 0.f ? s : 0.f;
    }
    __syncthreads();
    for (int k = 0; k < KN; ++k) {
        float s = b2[tid];
        for (int e = 0; e < D; ++e) s += sH[k][e] * W2[e * D + tid];
        sH2[k][tid] = s > 0.f ? s : 0.f;
    }
    __syncthreads();
    if (tid < KN) {
        float s = b3[0];
        for (int e = 0; e < D; ++e) s += sH2[tid][e] * W3[e];
        sS[tid] = s;
    }
    __syncthreads();
    if (tid == 0) {
        float mx = sS[0];
        for (int k = 1; k < KN; ++k) mx = fmaxf(mx, sS[k]);
        float sum = 0.f;
        for (int k = 0; k < KN; ++k) { sA2[k] = __expf(sS[k] - mx); sum += sA2[k]; }
        for (int k = 0; k < KN; ++k) sA2[k] /= sum;
    }
    __syncthreads();
    float a = 0.f;
    for (int k = 0; k < KN; ++k) a += sA2[k] * sE[k][tid];
    out[(long)node * D + tid] = a;
}

extern "C" void kernel_launch(void* const* d_in, const int* in_sizes, int n_in,
                              void* d_out, int out_size, void* d_ws, size_t ws_size,
                              hipStream_t stream) {
    const float* emb    = (const float*)d_in[0];
    const int*   vnodes = (const int*)d_in[1];
    const int*   nidx   = (const int*)d_in[2];
    const float* W1     = (const float*)d_in[3];
    const float* b1     = (const float*)d_in[4];
    const float* W2     = (const float*)d_in[5];
    const float* b2     = (const float*)d_in[6];
    const float* W3     = (const float*)d_in[7];
    const float* b3     = (const float*)d_in[8];
    float* out = (float*)d_out;

    const int NV = in_sizes[0] / D;   // 200000
    const int NN = in_sizes[1];       // 20000

    const size_t p1_elems = (size_t)NV * D;
    const size_t q_elems  = (size_t)NN * D;
    const size_t wt_elems = (size_t)D * D;
    const size_t need = (p1_elems + q_elems + 3 * wt_elems) * sizeof(unsigned short);

    if (ws_size >= need) {
        unsigned short* P1   = (unsigned short*)d_ws;
        unsigned short* Q    = P1 + p1_elems;
        unsigned short* W1Tt = Q + q_elems;
        unsigned short* W1Tb = W1Tt + wt_elems;
        unsigned short* W2T  = W1Tb + wt_elems;
        wt_kernel<<<(D * D + 255) / 256, 256, 0, stream>>>(W1, W2, W1Tt, W1Tb, W2T);
        p1q_kernel<<<(NV + 127) / 128, 256, 0, stream>>>(emb, nullptr, NV, W1Tt, nullptr, P1);
        p1q_kernel<<<(NN + 127) / 128, 256, 0, stream>>>(emb, vnodes, NN, W1Tb, b1, Q);
        agg_kernel<<<2048, 256, 0, stream>>>(emb, nidx, W2T, b2, W3, b3, P1, Q, out, NN);
    } else {
        naive_kernel<<<NN, D, 0, stream>>>(emb, vnodes, nidx, W1, b1, W2, b2, W3, b3, out);
    }
}

// Round 3
// 315.405 us; speedup vs baseline: 1.2226x; 1.0332x over previous
//
#include <hip/hip_runtime.h>
#include <hip/hip_bf16.h>

#define D  128
#define KN 32

typedef __attribute__((ext_vector_type(8))) short bf16x8;
typedef __attribute__((ext_vector_type(4))) float f32x4;

static __device__ __forceinline__ unsigned short f2bf(float f) {
    union { float f; unsigned int u; } v; v.f = f;
    unsigned int u = v.u;
    u += 0x7fff + ((u >> 16) & 1);   // round-to-nearest-even
    return (unsigned short)(u >> 16);
}
static __device__ __forceinline__ float bf2f(unsigned short h) {
    union { float f; unsigned int u; } v; v.u = ((unsigned int)h) << 16;
    return v.f;
}

// One-shot: transpose+convert W1 halves and W2 into bf16 [col][k] layouts so
// GEMM blocks load B-fragments straight from global (L2-resident).
__global__ __launch_bounds__(256) void wt_kernel(
    const float* __restrict__ W1, const float* __restrict__ W2,
    unsigned short* __restrict__ W1Tt, unsigned short* __restrict__ W1Tb,
    unsigned short* __restrict__ W2T)
{
    int idx = blockIdx.x * 256 + threadIdx.x;
    if (idx < D * D) {
        int col = idx >> 7, e = idx & 127;
        W1Tt[col * D + e] = f2bf(W1[e * D + col]);
        W1Tb[col * D + e] = f2bf(W1[(D + e) * D + col]);
        W2T [col * D + e] = f2bf(W2[e * D + col]);
    }
}

// dst[r][:] = (emb[gidx? gidx[r] : r] @ W) + bias   (bf16 out)
// 128 rows/block, B-frags register-resident. When EB != nullptr (identity
// pass) also emits the bf16 copy of emb rows (fused, coalesced from LDS).
__global__ __launch_bounds__(256) void p1q_kernel(
    const float* __restrict__ emb, const int* __restrict__ gidx, int M,
    const unsigned short* __restrict__ WT, const float* __restrict__ bias,
    unsigned short* __restrict__ dst, unsigned short* __restrict__ EB)
{
    __shared__ unsigned short sA[128][136];

    const int tid  = threadIdx.x;
    const int lane = tid & 63;
    const int w    = tid >> 6;
    const int m    = lane & 15, q = lane >> 4;
    const int r0   = blockIdx.x * 128;

    // stage 128 gathered rows fp32->bf16
#pragma unroll
    for (int i = 0; i < 16; ++i) {
        int e = tid + 256 * i;
        int row = e >> 5, c4 = (e & 31) << 2;
        int r = r0 + row; if (r > M - 1) r = M - 1;
        int vr = gidx ? gidx[r] : r;
        const float4 f = *(const float4*)(emb + (long)vr * D + c4);
        ushort4 h;
        h.x = f2bf(f.x); h.y = f2bf(f.y); h.z = f2bf(f.z); h.w = f2bf(f.w);
        *(ushort4*)(&sA[row][c4]) = h;
    }
    __syncthreads();

    // fused bf16-emb emission (identity pass only)
    if (EB) {
        int row = tid >> 1, half = tid & 1;
        if (r0 + row < M) {
#pragma unroll
            for (int j = 0; j < 8; ++j)
                *(bf16x8*)(EB + (long)(r0 + row) * D + half * 64 + j * 8) =
                    *(const bf16x8*)(&sA[row][half * 64 + j * 8]);
        }
    }

    bf16x8 Bf[2][4];
#pragma unroll
    for (int nt = 0; nt < 2; ++nt)
#pragma unroll
        for (int kk = 0; kk < 4; ++kk)
            Bf[nt][kk] = *(const bf16x8*)(WT + (32 * w + 16 * nt + m) * D + kk * 32 + q * 8);
    float bv[2];
#pragma unroll
    for (int nt = 0; nt < 2; ++nt) bv[nt] = bias ? bias[32 * w + 16 * nt + m] : 0.f;

    f32x4 acc[8][2];
#pragma unroll
    for (int mt = 0; mt < 8; ++mt)
#pragma unroll
        for (int nt = 0; nt < 2; ++nt) acc[mt][nt] = (f32x4){0.f, 0.f, 0.f, 0.f};

#pragma unroll
    for (int kk = 0; kk < 4; ++kk) {
#pragma unroll
        for (int mt = 0; mt < 8; ++mt) {
            bf16x8 a = *(const bf16x8*)(&sA[16 * mt + m][kk * 32 + q * 8]);
            acc[mt][0] = __builtin_amdgcn_mfma_f32_16x16x32_bf16(a, Bf[0][kk], acc[mt][0], 0, 0, 0);
            acc[mt][1] = __builtin_amdgcn_mfma_f32_16x16x32_bf16(a, Bf[1][kk], acc[mt][1], 0, 0, 0);
        }
    }

    // C/D layout: col=lane&15, row=(lane>>4)*4+reg
#pragma unroll
    for (int mt = 0; mt < 8; ++mt)
#pragma unroll
        for (int nt = 0; nt < 2; ++nt) {
            int col = 32 * w + 16 * nt + m;
#pragma unroll
            for (int r = 0; r < 4; ++r) {
                int row = r0 + 16 * mt + 4 * q + r;
                if (row < M) dst[(long)row * D + col] = f2bf(acc[mt][nt][r] + bv[nt]);
            }
        }
}

// Fused per-node: X = relu(P1[nidx]+Q[node]); h2 = relu(X@W2+b2);
// score = h2@W3+b3; softmax; out = sum_k att_k * emb[nidx[k]].
// 4 nodes per iteration (128-row GEMM). Aggregation gather prefetched
// before the MFMA loop (bf16 EB path) to hide random-gather latency.
template <bool USE_EB>
__global__ __launch_bounds__(256, 3) void agg_kernel(
    const float* __restrict__ emb, const unsigned short* __restrict__ EB,
    const int* __restrict__ nidx,
    const unsigned short* __restrict__ W2T,
    const float* __restrict__ b2, const float* __restrict__ W3,
    const float* __restrict__ b3,
    const unsigned short* __restrict__ P1, const unsigned short* __restrict__ Q,
    float* __restrict__ out, int NN)
{
    __shared__ unsigned short sX[128][136];
    __shared__ int   sIdx[128];
    __shared__ float sSp[4][128];
    __shared__ float sAtt[128];

    const int tid  = threadIdx.x;
    const int lane = tid & 63;
    const int w    = tid >> 6;          // wave index == node sub-index
    const int m    = lane & 15, q = lane >> 4;

    bf16x8 Bf[2][4];
#pragma unroll
    for (int nt = 0; nt < 2; ++nt)
#pragma unroll
        for (int kk = 0; kk < 4; ++kk)
            Bf[nt][kk] = *(const bf16x8*)(W2T + (32 * w + 16 * nt + m) * D + kk * 32 + q * 8);
    float b2v[2], w3v[2];
#pragma unroll
    for (int nt = 0; nt < 2; ++nt) {
        int col = 32 * w + 16 * nt + m;
        b2v[nt] = b2[col];
        w3v[nt] = W3[col];
    }
    const float b3s = b3[0];

    const int groups = (NN + 3) >> 2;
    for (int g = blockIdx.x; g < groups; g += gridDim.x) {
        const int node0 = g * 4;

        // ---- stage 128 rows (4 nodes x 32 neighbors), 2 threads/row ----
        {
            int row = tid >> 1, half = tid & 1;
            int nd = node0 + (row >> 5); if (nd > NN - 1) nd = NN - 1;
            int k = row & 31;
            int ni = nidx[nd * KN + k];
            if (half == 0) sIdx[row] = ni;
            const bf16x8* pp = (const bf16x8*)(P1 + (long)ni * D) + half * 8;
            const bf16x8* qq = (const bf16x8*)(Q + (long)nd * D) + half * 8;
#pragma unroll
            for (int j = 0; j < 8; ++j) {
                bf16x8 p = pp[j], qv = qq[j], r;
#pragma unroll
                for (int h = 0; h < 8; ++h) {
                    float v = bf2f((unsigned short)p[h]) + bf2f((unsigned short)qv[h]);
                    r[h] = (short)f2bf(v > 0.f ? v : 0.f);
                }
                *(bf16x8*)(&sX[row][half * 64 + j * 8]) = r;
            }
        }
        __syncthreads();

        // ---- prefetch aggregation gather (node w, this wave) ----
        // lane covers cols 8*(lane&15).. for k = (lane>>4)+4j
        bf16x8 gv[8];
        if (USE_EB) {
#pragma unroll
            for (int j = 0; j < 8; ++j) {
                int k = (lane >> 4) + 4 * j;
                int ni = sIdx[w * KN + k];
                gv[j] = *(const bf16x8*)(EB + (long)ni * D + (lane & 15) * 8);
            }
        }

        // ---- layer-2 GEMM: 8 M-tiles x this wave's 2 N-tiles ----
        f32x4 acc[8][2];
#pragma unroll
        for (int mt = 0; mt < 8; ++mt)
#pragma unroll
            for (int nt = 0; nt < 2; ++nt) acc[mt][nt] = (f32x4){0.f, 0.f, 0.f, 0.f};

#pragma unroll
        for (int kk = 0; kk < 4; ++kk) {
#pragma unroll
            for (int mt = 0; mt < 8; ++mt) {
                bf16x8 a = *(const bf16x8*)(&sX[16 * mt + m][kk * 32 + q * 8]);
                acc[mt][0] = __builtin_amdgcn_mfma_f32_16x16x32_bf16(a, Bf[0][kk], acc[mt][0], 0, 0, 0);
                acc[mt][1] = __builtin_amdgcn_mfma_f32_16x16x32_bf16(a, Bf[1][kk], acc[mt][1], 0, 0, 0);
            }
        }

        // ---- relu+bias, dot W3, reduce across 16 col-lanes ----
#pragma unroll
        for (int mt = 0; mt < 8; ++mt) {
            float p[4];
#pragma unroll
            for (int r = 0; r < 4; ++r) {
                float h0 = acc[mt][0][r] + b2v[0]; h0 = h0 > 0.f ? h0 : 0.f;
                float h1 = acc[mt][1][r] + b2v[1]; h1 = h1 > 0.f ? h1 : 0.f;
                p[r] = h0 * w3v[0] + h1 * w3v[1];
            }
#pragma unroll
            for (int off = 8; off >= 1; off >>= 1)
#pragma unroll
                for (int r = 0; r < 4; ++r) p[r] += __shfl_xor(p[r], off, 16);
            if (m == 0) {
#pragma unroll
                for (int r = 0; r < 4; ++r) sSp[w][16 * mt + 4 * q + r] = p[r];
            }
        }
        __syncthreads();

        // ---- softmax: 128 scores = 4 nodes x 32 neighbors ----
        if (tid < 128) {
            float s = sSp[0][tid] + sSp[1][tid] + sSp[2][tid] + sSp[3][tid] + b3s;
            float mx = s;
#pragma unroll
            for (int off = 16; off >= 1; off >>= 1) mx = fmaxf(mx, __shfl_xor(mx, off, 32));
            float e = __expf(s - mx);
            float sum = e;
#pragma unroll
            for (int off = 16; off >= 1; off >>= 1) sum += __shfl_xor(sum, off, 32);
            sAtt[tid] = e / sum;
        }
        __syncthreads();

        // ---- aggregation: node w per wave ----
        if (USE_EB) {
            float r[8] = {0.f, 0.f, 0.f, 0.f, 0.f, 0.f, 0.f, 0.f};
#pragma unroll
            for (int j = 0; j < 8; ++j) {
                float a = sAtt[w * KN + (lane >> 4) + 4 * j];
#pragma unroll
                for (int h = 0; h < 8; ++h)
                    r[h] += a * bf2f((unsigned short)gv[j][h]);
            }
#pragma unroll
            for (int h = 0; h < 8; ++h) {
                r[h] += __shfl_xor(r[h], 16);
                r[h] += __shfl_xor(r[h], 32);
            }
            int nd = node0 + w;
            if (lane < 16 && nd < NN) {
                float4 o0 = {r[0], r[1], r[2], r[3]};
                float4 o1 = {r[4], r[5], r[6], r[7]};
                *(float4*)(out + (long)nd * D + lane * 8)     = o0;
                *(float4*)(out + (long)nd * D + lane * 8 + 4) = o1;
            }
        } else {
            float a0 = 0.f, a1 = 0.f;
            for (int k = 0; k < KN; ++k) {
                float att = sAtt[w * KN + k];
                const float* er = emb + (long)sIdx[w * KN + k] * D;
                a0 += att * er[lane];
                a1 += att * er[lane + 64];
            }
            int nd = node0 + w;
            if (nd < NN) {
                out[(long)nd * D + lane]      = a0;
                out[(long)nd * D + lane + 64] = a1;
            }
        }
        __syncthreads();   // protect shared buffers before next iteration
    }
}

// Correct-but-slow fp32 VALU fallback (only if ws is too small).
__global__ __launch_bounds__(128) void naive_kernel(
    const float* __restrict__ emb, const int* __restrict__ vnodes,
    const int* __restrict__ nidx,
    const float* __restrict__ W1, const float* __restrict__ b1,
    const float* __restrict__ W2, const float* __restrict__ b2,
    const float* __restrict__ W3, const float* __restrict__ b3,
    float* __restrict__ out)
{
    __shared__ float sE[KN + 1][D];
    __shared__ float sH[KN][D];
    __shared__ float sH2[KN][D];
    __shared__ float sS[KN];
    __shared__ float sA2[KN];
    const int node = blockIdx.x, tid = threadIdx.x;

    for (int r = 0; r < KN + 1; ++r) {
        int vr = (r < KN) ? nidx[node * KN + r] : vnodes[node];
        sE[r][tid] = emb[(long)vr * D + tid];
    }
    __syncthreads();
    for (int k = 0; k < KN; ++k) {
        float s = b1[tid];
        for (int e = 0; e < D; ++e) s += sE[k][e]  * W1[e * D + tid];
        for (int e = 0; e < D; ++e) s += sE[KN][e] * W1[(D + e) * D + tid];
        sH[k][tid] = s > 0.f ? s : 0.f;
    }
    __syncthreads();
    for (int k = 0; k < KN; ++k) {
        float s = b2[tid];
        for (int e = 0; e < D; ++e) s += sH[k][e] * W2[e * D + tid];
        sH2[k][tid] = s > 0.f ? s : 0.f;
    }
    __syncthreads();
    if (tid < KN) {
        float s = b3[0];
        for (int e = 0; e < D; ++e) s += sH2[tid][e] * W3[e];
        sS[tid] = s;
    }
    __syncthreads();
    if (tid == 0) {
        float mx = sS[0];
        for (int k = 1; k < KN; ++k) mx = fmaxf(mx, sS[k]);
        float sum = 0.f;
        for (int k = 0; k < KN; ++k) { sA2[k] = __expf(sS[k] - mx); sum += sA2[k]; }
        for (int k = 0; k < KN; ++k) sA2[k] /= sum;
    }
    __syncthreads();
    float a = 0.f;
    for (int k = 0; k < KN; ++k) a += sA2[k] * sE[k][tid];
    out[(long)node * D + tid] = a;
}

extern "C" void kernel_launch(void* const* d_in, const int* in_sizes, int n_in,
                              void* d_out, int out_size, void* d_ws, size_t ws_size,
                              hipStream_t stream) {
    const float* emb    = (const float*)d_in[0];
    const int*   vnodes = (const int*)d_in[1];
    const int*   nidx   = (const int*)d_in[2];
    const float* W1     = (const float*)d_in[3];
    const float* b1     = (const float*)d_in[4];
    const float* W2     = (const float*)d_in[5];
    const float* b2     = (const float*)d_in[6];
    const float* W3     = (const float*)d_in[7];
    const float* b3     = (const float*)d_in[8];
    float* out = (float*)d_out;

    const int NV = in_sizes[0] / D;   // 200000
    const int NN = in_sizes[1];       // 20000

    const size_t p1_elems = (size_t)NV * D;
    const size_t q_elems  = (size_t)NN * D;
    const size_t wt_elems = (size_t)D * D;
    const size_t base_elems = p1_elems + q_elems + 3 * wt_elems;
    const size_t need_base = base_elems * sizeof(unsigned short);
    const size_t need_eb   = (base_elems + p1_elems) * sizeof(unsigned short);

    if (ws_size >= need_base) {
        unsigned short* P1   = (unsigned short*)d_ws;
        unsigned short* Q    = P1 + p1_elems;
        unsigned short* W1Tt = Q + q_elems;
        unsigned short* W1Tb = W1Tt + wt_elems;
        unsigned short* W2T  = W1Tb + wt_elems;
        unsigned short* EB   = (ws_size >= need_eb) ? (W2T + wt_elems) : nullptr;

        wt_kernel<<<(D * D + 255) / 256, 256, 0, stream>>>(W1, W2, W1Tt, W1Tb, W2T);
        p1q_kernel<<<(NV + 127) / 128, 256, 0, stream>>>(emb, nullptr, NV, W1Tt, nullptr, P1, EB);
        p1q_kernel<<<(NN + 127) / 128, 256, 0, stream>>>(emb, vnodes, NN, W1Tb, b1, Q, nullptr);
        if (EB)
            agg_kernel<true><<<2048, 256, 0, stream>>>(emb, EB, nidx, W2T, b2, W3, b3, P1, Q, out, NN);
        else
            agg_kernel<false><<<2048, 256, 0, stream>>>(emb, nullptr, nidx, W2T, b2, W3, b3, P1, Q, out, NN);
    } else {
        naive_kernel<<<NN, D, 0, stream>>>(emb, vnodes, nidx, W1, b1, W2, b2, W3, b3, out);
    }
}